// Round 8
// baseline (180.287 us; speedup 1.0000x reference)
//
#include <hip/hip_runtime.h>
#include <math.h>

#define B_    16
#define N_    8192
#define D_    256
#define BN_   32
#define R_    4
#define LOGN  13

typedef float  f32x4  __attribute__((ext_vector_type(4)));
typedef short  s16x8  __attribute__((ext_vector_type(8)));

// ---------------------------------------------------------------------------
// Morton helpers (exact replica of reference bit-interleave)
// ---------------------------------------------------------------------------
__device__ __forceinline__ unsigned long long interleave3(unsigned long long v) {
    v = v & 2097151ULL;
    v = v | (v << 32);
    v = v & 8725724278095871ULL;
    v = v | ((v << 16) & 8725728556220671ULL);
    v = v | ((v << 8)  & 282506020581391ULL);
    v = v | ((v << 4)  & 294878547030211ULL);
    v = v | ((v << 2)  & 321685687669321ULL);
    return v;
}

__device__ __forceinline__ long long quant10(float c) {
    long long v = (long long)(c * 1023.0f);
    v = v < 0 ? 0 : (v > 1023 ? 1023 : v);
    return v;
}

__device__ __forceinline__ unsigned short f2bf(float f) {
    unsigned u = __float_as_uint(f);
    u = (u + 0x7FFF + ((u >> 16) & 1)) >> 16;   // RNE
    return (unsigned short)u;
}

// packed RNE f32x2 -> bf16x2 (single HW op)
__device__ __forceinline__ unsigned cvtpk_bf16(float lo, float hi) {
    unsigned r;
    asm("v_cvt_pk_bf16_f32 %0, %1, %2" : "=v"(r) : "v"(lo), "v"(hi));
    return r;
}

// ---------------------------------------------------------------------------
// P0: prep — G = Wu @ V  [256,4]  and  Wd packed to bf16 [32][256] row-major.
// ---------------------------------------------------------------------------
__global__ void prep_kernel(const float* __restrict__ Wu, const float* __restrict__ V,
                            const float* __restrict__ Wd,
                            float* __restrict__ G, unsigned short* __restrict__ wdpack) {
    const int t = threadIdx.x;   // 256
    for (int r = 0; r < R_; ++r) {
        float s = 0.0f;
        for (int kk = 0; kk < BN_; ++kk) s += Wu[t * BN_ + kk] * V[kk * R_ + r];
        G[t * R_ + r] = s;
    }
    for (int i = t; i < BN_ * 256; i += 256) {
        const int row = i >> 8, col = i & 255;
        wdpack[i] = f2bf(Wd[row * 257 + col]);
    }
}

// ---------------------------------------------------------------------------
// S1: 32 blocks (b, half). Bitonic phases size=2..4096 on 4096 keys in LDS.
// ---------------------------------------------------------------------------
__global__ __launch_bounds__(1024)
void sort1_kernel(const float* __restrict__ coords, unsigned long long* __restrict__ keys) {
    __shared__ unsigned long long skey[4096];    // 32 KB
    const int b = blockIdx.x >> 1;
    const int h = blockIdx.x & 1;
    const int t = threadIdx.x;
    const int gbase = h * 4096;

    for (int i = t; i < 4096; i += 1024) {
        const int gi = gbase + i;
        const float* c = coords + ((size_t)b * N_ + gi) * 3;
        unsigned long long mx = interleave3((unsigned long long)quant10(c[0]));
        unsigned long long my = interleave3((unsigned long long)quant10(c[1]));
        unsigned long long mz = interleave3((unsigned long long)quant10(c[2]));
        unsigned long long m = mx | (my << 1) | (mz << 2);
        skey[i] = (m << LOGN) | (unsigned long long)gi;
    }
    __syncthreads();

    for (int size = 2; size <= 4096; size <<= 1) {
        for (int s = size >> 1; s > 0; s >>= 1) {
            int i_[2];
            unsigned long long a_[2], b_[2];
            #pragma unroll
            for (int u = 0; u < 2; ++u) {
                int p  = t + u * 1024;
                int jj = p & (s - 1);
                int i  = ((p - jj) << 1) + jj;
                i_[u] = i; a_[u] = skey[i]; b_[u] = skey[i + s];
            }
            #pragma unroll
            for (int u = 0; u < 2; ++u) {
                bool up = (((gbase + i_[u]) & size) == 0);
                unsigned long long lo = a_[u] < b_[u] ? a_[u] : b_[u];
                unsigned long long hi = a_[u] < b_[u] ? b_[u] : a_[u];
                skey[i_[u]]     = up ? lo : hi;
                skey[i_[u] + s] = up ? hi : lo;
            }
            __syncthreads();
        }
    }
    for (int i = t; i < 4096; i += 1024)
        keys[(size_t)b * N_ + gbase + i] = skey[i];
}

// ---------------------------------------------------------------------------
// S2a: global stride-4096 compare-swap (final merge, first stage).
// ---------------------------------------------------------------------------
__global__ __launch_bounds__(256)
void sort2a_kernel(unsigned long long* __restrict__ keys) {
    const int tid = blockIdx.x * 256 + threadIdx.x;   // 65536
    const int b = tid >> 12;
    const int i = tid & 4095;
    unsigned long long* kb = keys + (size_t)b * N_;
    unsigned long long a = kb[i], c = kb[i + 4096];
    kb[i]        = a < c ? a : c;
    kb[i + 4096] = a < c ? c : a;
}

// ---------------------------------------------------------------------------
// S2b: 32 blocks (b, half). Final-merge strides 2048..1 within each half.
// Emits INVERSE permutation: inv[b][natural] = sorted position.
// ---------------------------------------------------------------------------
__global__ __launch_bounds__(1024)
void sort2b_kernel(const unsigned long long* __restrict__ keys, int* __restrict__ inv) {
    __shared__ unsigned long long skey[4096];    // 32 KB
    const int b = blockIdx.x >> 1;
    const int h = blockIdx.x & 1;
    const int t = threadIdx.x;
    const int gbase = h * 4096;

    for (int i = t; i < 4096; i += 1024) skey[i] = keys[(size_t)b * N_ + gbase + i];
    __syncthreads();

    for (int s = 2048; s > 0; s >>= 1) {
        int i_[2];
        unsigned long long a_[2], b_[2];
        #pragma unroll
        for (int u = 0; u < 2; ++u) {
            int p  = t + u * 1024;
            int jj = p & (s - 1);
            int i  = ((p - jj) << 1) + jj;
            i_[u] = i; a_[u] = skey[i]; b_[u] = skey[i + s];
        }
        #pragma unroll
        for (int u = 0; u < 2; ++u) {
            unsigned long long lo = a_[u] < b_[u] ? a_[u] : b_[u];
            unsigned long long hi = a_[u] < b_[u] ? b_[u] : a_[u];
            skey[i_[u]]     = lo;
            skey[i_[u] + s] = hi;
        }
        __syncthreads();
    }
    for (int i = t; i < 4096; i += 1024)
        inv[b * N_ + (int)(skey[i] & (unsigned long long)(N_ - 1))] = gbase + i;
}

// ---------------------------------------------------------------------------
// K2 (MFMA): NATURAL-order x stream (perfectly coalesced); output scattered
// as one fully-dirty 128B block per point into z_pk[b][p][32] (no RMW).
// Wd A-fragments in registers from bf16 pack; x staged in LDS (32 KB).
// ---------------------------------------------------------------------------
__global__ __launch_bounds__(256)
void zgemm_kernel(const float* __restrict__ x,
                  const float* __restrict__ coords,
                  const float* __restrict__ Wd,
                  const float* __restrict__ bd,
                  const int*   __restrict__ inv,
                  const unsigned short* __restrict__ wdpack,
                  float*       __restrict__ z_pk) {
    __shared__ char xlds[64 * 256 * 2];    // 32 KB
    __shared__ float sWdLast[BN_];
    __shared__ float sbd[BN_];

    const int blk = blockIdx.x;           // 2048 = 16 * 128
    const int b   = blk >> 7;
    const int m0  = (blk & 127) << 6;     // natural row base
    const int t   = threadIdx.x;
    const int w   = t >> 6;
    const int l   = t & 63;
    const int lg  = l >> 4;
    const int lm  = l & 15;

    s16x8 wf0[8], wf1[8];
    #pragma unroll
    for (int kc = 0; kc < 8; ++kc) {
        wf0[kc] = *(const s16x8*)(wdpack + lm * 256        + kc * 32 + lg * 8);
        wf1[kc] = *(const s16x8*)(wdpack + (lm + 16) * 256 + kc * 32 + lg * 8);
    }

    // ---- stage x tile: pure streaming (natural rows) ----
    for (int rr_ = 0; rr_ < 16; ++rr_) {
        const int row = rr_ * 4 + w;
        const float4 v = *(const float4*)(x + ((size_t)(b * N_ + m0 + row)) * D_ + l * 4);
        unsigned off = (row << 9) + (l << 3);
        off ^= (row & 7) << 4;
        uint2 pk = make_uint2(cvtpk_bf16(v.x, v.y), cvtpk_bf16(v.z, v.w));
        *(uint2*)(xlds + off) = pk;
    }
    if (t < BN_) { sWdLast[t] = Wd[(size_t)t * 257 + 256]; sbd[t] = bd[t]; }
    __syncthreads();

    f32x4 acc0 = {0.f, 0.f, 0.f, 0.f};
    f32x4 acc1 = {0.f, 0.f, 0.f, 0.f};
    const int xr = w * 16 + lm;
    #pragma unroll
    for (int kc = 0; kc < 8; ++kc) {
        const unsigned doff = kc * 64 + lg * 16;
        s16x8 bfr = *(const s16x8*)(xlds + ((((unsigned)xr << 9) + doff) ^ ((xr & 7) << 4)));
        acc0 = __builtin_amdgcn_mfma_f32_16x16x32_bf16(wf0[kc], bfr, acc0, 0, 0, 0);
        acc1 = __builtin_amdgcn_mfma_f32_16x16x32_bf16(wf1[kc], bfr, acc1, 0, 0, 0);
    }

    // ---- epilogue: radius (at target slot) + bias, relu, 128B-block store ----
    const int m = m0 + w * 16 + lm;                  // natural row
    const int p = inv[b * N_ + m];                   // sorted position
    const float* c = coords + ((size_t)(b * N_ + p)) * 3;
    const float rr = sqrtf(c[0] * c[0] + c[1] * c[1] + c[2] * c[2]);
    float* zb = z_pk + ((size_t)(b * N_ + p)) * BN_;
    float4 v0, v1;
    v0.x = fmaxf(acc0[0] + rr * sWdLast[lg * 4 + 0] + sbd[lg * 4 + 0], 0.0f);
    v0.y = fmaxf(acc0[1] + rr * sWdLast[lg * 4 + 1] + sbd[lg * 4 + 1], 0.0f);
    v0.z = fmaxf(acc0[2] + rr * sWdLast[lg * 4 + 2] + sbd[lg * 4 + 2], 0.0f);
    v0.w = fmaxf(acc0[3] + rr * sWdLast[lg * 4 + 3] + sbd[lg * 4 + 3], 0.0f);
    v1.x = fmaxf(acc1[0] + rr * sWdLast[16 + lg * 4 + 0] + sbd[16 + lg * 4 + 0], 0.0f);
    v1.y = fmaxf(acc1[1] + rr * sWdLast[16 + lg * 4 + 1] + sbd[16 + lg * 4 + 1], 0.0f);
    v1.z = fmaxf(acc1[2] + rr * sWdLast[16 + lg * 4 + 2] + sbd[16 + lg * 4 + 2], 0.0f);
    v1.w = fmaxf(acc1[3] + rr * sWdLast[16 + lg * 4 + 3] + sbd[16 + lg * 4 + 3], 0.0f);
    *(float4*)(zb + lg * 4)      = v0;
    *(float4*)(zb + 16 + lg * 4) = v1;
}

// ---------------------------------------------------------------------------
// ZT: transpose z_pk[b][p][32] -> z_kp[b][k][p]. LDS tile 64 points x 32 ch.
// Both sides fully coalesced.
// ---------------------------------------------------------------------------
__global__ __launch_bounds__(256)
void ztr_kernel(const float* __restrict__ z_pk, float* __restrict__ z_kp) {
    __shared__ float ltile[64][33];
    const int blk = blockIdx.x;           // 2048
    const int b   = blk >> 7;
    const int p0  = (blk & 127) << 6;
    const int t   = threadIdx.x;

    #pragma unroll
    for (int u = 0; u < 2; ++u) {
        const int idx = t + u * 256;      // 512 float4 loads
        const int pl  = idx >> 3, kc = idx & 7;
        const float4 v = *(const float4*)(z_pk + ((size_t)(b * N_ + p0 + pl)) * BN_ + kc * 4);
        ltile[pl][kc * 4 + 0] = v.x;
        ltile[pl][kc * 4 + 1] = v.y;
        ltile[pl][kc * 4 + 2] = v.z;
        ltile[pl][kc * 4 + 3] = v.w;
    }
    __syncthreads();

    #pragma unroll
    for (int u = 0; u < 2; ++u) {
        const int idx = t + u * 256;      // 512 float4 stores
        const int k   = idx >> 4, pc = idx & 15;
        float4 v;
        v.x = ltile[pc * 4 + 0][k];
        v.y = ltile[pc * 4 + 1][k];
        v.z = ltile[pc * 4 + 2][k];
        v.w = ltile[pc * 4 + 3][k];
        *(float4*)(z_kp + (size_t)(b * BN_ + k) * N_ + p0 + pc * 4) = v;
    }
}

// ---------------------------------------------------------------------------
// K4: PAIR-PACKED spectral filter (unchanged from round 7).
// ---------------------------------------------------------------------------
__device__ __forceinline__ float2 cmul(float2 a, float2 b) {
    return make_float2(a.x * b.x - a.y * b.y, a.x * b.y + a.y * b.x);
}
__device__ __forceinline__ float2 sdmix(float S, float D, float2 P, float2 Q) {
    return make_float2(S * P.x + D * Q.x, S * P.y - D * Q.y);
}

__global__ __launch_bounds__(512)
void fft_filter_kernel(float* __restrict__ zy,
                       const float* __restrict__ logit_d) {
    extern __shared__ float2 cbuf[];   // 64 KB

    const int bk = blockIdx.x;     // 256 = B_ * 16
    const int b  = bk >> 4;
    const int kp = bk & 15;
    const int t  = threadIdx.x;

    float* row1 = zy + (size_t)(b * BN_ + 2 * kp) * N_;
    float* row2 = row1 + N_;

    float d1 = fminf(fmaxf(logit_d[2 * kp],     -10.0f), 10.0f);
    float d2 = fminf(fmaxf(logit_d[2 * kp + 1], -10.0f), 10.0f);

    const float cpi  = 3.14159265358979323846f;
    const float c2pi = 6.28318530717958647692f;
    const float A    = c2pi * 8192.0f / 8191.0f;

    const float Eh1 = __expf(-0.5f * A * d1), E1 = Eh1 * Eh1;
    const float Eh2 = __expf(-0.5f * A * d2), E2 = Eh2 * Eh2;

    {
        const int h = 4096, hh = 2048;
        #pragma unroll
        for (int u = 0; u < 4; ++u) {
            const int i0 = t + u * 512;
            float2 c0 = make_float2(row1[i0],            row2[i0]);
            float2 c1 = make_float2(row1[i0 + hh],       row2[i0 + hh]);
            float2 c2 = make_float2(row1[i0 + h],        row2[i0 + h]);
            float2 c3 = make_float2(row1[i0 + h + hh],   row2[i0 + h + hh]);
            float sA, cA;
            __sincosf(-cpi * (float)i0 / (float)h, &sA, &cA);
            const float2 twA1 = make_float2(cA, sA);
            const float2 twA2 = make_float2(sA, -cA);
            const float2 twB  = make_float2(2.0f * cA * cA - 1.0f, 2.0f * sA * cA);
            float2 a0 = make_float2(c0.x + c2.x, c0.y + c2.y);
            float2 a1 = make_float2(c1.x + c3.x, c1.y + c3.y);
            float2 b0 = cmul(make_float2(c0.x - c2.x, c0.y - c2.y), twA1);
            float2 b1 = cmul(make_float2(c1.x - c3.x, c1.y - c3.y), twA2);
            cbuf[i0]          = make_float2(a0.x + a1.x, a0.y + a1.y);
            cbuf[i0 + hh]     = cmul(make_float2(a0.x - a1.x, a0.y - a1.y), twB);
            cbuf[i0 + h]      = make_float2(b0.x + b1.x, b0.y + b1.y);
            cbuf[i0 + h + hh] = cmul(make_float2(b0.x - b1.x, b0.y - b1.y), twB);
        }
        __syncthreads();
    }

    #pragma unroll
    for (int h = 1024; h >= 4; h >>= 2) {
        const int hh = h >> 1;
        #pragma unroll
        for (int u = 0; u < 4; ++u) {
            const int q   = t + u * 512;
            const int jj  = q & (hh - 1);
            const int i0  = ((q - jj) << 2) + jj;
            float2 c0 = cbuf[i0];
            float2 c1 = cbuf[i0 + hh];
            float2 c2 = cbuf[i0 + h];
            float2 c3 = cbuf[i0 + h + hh];
            float sA, cA;
            __sincosf(-cpi * (float)jj / (float)h, &sA, &cA);
            const float2 twA1 = make_float2(cA, sA);
            const float2 twA2 = make_float2(sA, -cA);
            const float2 twB  = make_float2(2.0f * cA * cA - 1.0f, 2.0f * sA * cA);
            float2 a0 = make_float2(c0.x + c2.x, c0.y + c2.y);
            float2 a1 = make_float2(c1.x + c3.x, c1.y + c3.y);
            float2 b0 = cmul(make_float2(c0.x - c2.x, c0.y - c2.y), twA1);
            float2 b1 = cmul(make_float2(c1.x - c3.x, c1.y - c3.y), twA2);
            cbuf[i0]          = make_float2(a0.x + a1.x, a0.y + a1.y);
            cbuf[i0 + hh]     = cmul(make_float2(a0.x - a1.x, a0.y - a1.y), twB);
            cbuf[i0 + h]      = make_float2(b0.x + b1.x, b0.y + b1.y);
            cbuf[i0 + h + hh] = cmul(make_float2(b0.x - b1.x, b0.y - b1.y), twB);
        }
        __syncthreads();
    }

    {
        #pragma unroll
        for (int v = 0; v < 4; ++v) {
            const int u = t + v * 512;
            if (u == 0) {
                {
                    float2 g0 = cbuf[0], g1 = cbuf[1];
                    float2 Pa = make_float2(g0.x + g1.x, g0.y + g1.y);
                    float2 Pb = make_float2(g0.x - g1.x, g0.y - g1.y);
                    float2 Ra = Pa;
                    float Sb = 0.5f * (Eh1 + Eh2), Db = 0.5f * (Eh1 - Eh2);
                    float2 Rb = sdmix(Sb, Db, Pb, Pb);
                    cbuf[0] = make_float2(Ra.x + Rb.x, Ra.y + Rb.y);
                    cbuf[1] = make_float2(Ra.x - Rb.x, Ra.y - Rb.y);
                }
                {
                    float wu = c2pi * 2048.0f / 8191.0f;
                    float h1 = __expf(-wu * d1), h2 = __expf(-wu * d2);
                    float h1b = h1 * Eh1, h2b = h2 * Eh2;
                    float Hs1a = 0.5f * (h1 + E1 / h1);
                    float Hs2a = 0.5f * (h2 + E2 / h2);
                    float Hs1b = 0.5f * (h1b + E1 / h1b);
                    float Hs2b = 0.5f * (h2b + E2 / h2b);
                    float Sa = 0.5f * (Hs1a + Hs2a), Da = 0.5f * (Hs1a - Hs2a);
                    float Sb = 0.5f * (Hs1b + Hs2b), Db = 0.5f * (Hs1b - Hs2b);
                    float2 g0 = cbuf[2], g1 = cbuf[3];
                    float2 Pa = make_float2(g0.x + g1.x, g0.y + g1.y);
                    float2 Pb = make_float2(g0.x - g1.x, g0.y - g1.y);
                    float2 Ra = sdmix(Sa, Da, Pa, Pb);
                    float2 Rb = sdmix(Sb, Db, Pb, Pa);
                    cbuf[2] = make_float2(Ra.x + Rb.x, Ra.y + Rb.y);
                    cbuf[3] = make_float2(Ra.x - Rb.x, Ra.y - Rb.y);
                }
            } else {
                const int u2 = 4096 - u;
                const int c  = (int)(__brev((unsigned)u)  >> 20);
                const int c2 = (int)(__brev((unsigned)u2) >> 20);
                float2 g0 = cbuf[2 * c],  g1 = cbuf[2 * c + 1];
                float2 q0 = cbuf[2 * c2], q1 = cbuf[2 * c2 + 1];
                float2 Pa  = make_float2(g0.x + g1.x, g0.y + g1.y);
                float2 Pb  = make_float2(g0.x - g1.x, g0.y - g1.y);
                float2 Pa2 = make_float2(q0.x + q1.x, q0.y + q1.y);
                float2 Pb2 = make_float2(q0.x - q1.x, q0.y - q1.y);
                float wu = c2pi * (float)u / 8191.0f;
                float h1 = __expf(-wu * d1), h2 = __expf(-wu * d2);
                float h1b = h1 * Eh1, h2b = h2 * Eh2;
                float Hs1a = 0.5f * (h1 + E1 / h1);
                float Hs2a = 0.5f * (h2 + E2 / h2);
                float Hs1b = 0.5f * (h1b + E1 / h1b);
                float Hs2b = 0.5f * (h2b + E2 / h2b);
                float Sa = 0.5f * (Hs1a + Hs2a), Da = 0.5f * (Hs1a - Hs2a);
                float Sb = 0.5f * (Hs1b + Hs2b), Db = 0.5f * (Hs1b - Hs2b);
                float2 Ra  = sdmix(Sa, Da, Pa,  Pb2);
                float2 Rb2 = sdmix(Sa, Da, Pb2, Pa);
                float2 Rb  = sdmix(Sb, Db, Pb,  Pa2);
                float2 Ra2 = sdmix(Sb, Db, Pa2, Pb);
                cbuf[2 * c]      = make_float2(Ra.x + Rb.x,   Ra.y + Rb.y);
                cbuf[2 * c + 1]  = make_float2(Ra.x - Rb.x,   Ra.y - Rb.y);
                cbuf[2 * c2]     = make_float2(Ra2.x + Rb2.x, Ra2.y + Rb2.y);
                cbuf[2 * c2 + 1] = make_float2(Ra2.x - Rb2.x, Ra2.y - Rb2.y);
            }
        }
        __syncthreads();
    }

    #pragma unroll
    for (int h = 2; h <= 512; h <<= 2) {
        #pragma unroll
        for (int u = 0; u < 4; ++u) {
            const int q  = t + u * 512;
            const int jj = q & (h - 1);
            const int i0 = ((q - jj) << 2) + jj;
            float2 c0 = cbuf[i0];
            float2 c1 = cbuf[i0 + h];
            float2 c2 = cbuf[i0 + 2 * h];
            float2 c3 = cbuf[i0 + 3 * h];
            float sa, ca;
            __sincosf(cpi * (float)jj / (float)(2 * h), &sa, &ca);
            const float2 tw1  = make_float2(2.0f * ca * ca - 1.0f, 2.0f * sa * ca);
            const float2 tw2a = make_float2(ca, sa);
            const float2 tw2b = make_float2(-sa, ca);
            float2 t0 = cmul(c1, tw1);
            float2 a0 = make_float2(c0.x + t0.x, c0.y + t0.y);
            float2 a1 = make_float2(c0.x - t0.x, c0.y - t0.y);
            float2 t1 = cmul(c3, tw1);
            float2 b0 = make_float2(c2.x + t1.x, c2.y + t1.y);
            float2 b1 = make_float2(c2.x - t1.x, c2.y - t1.y);
            float2 t2 = cmul(b0, tw2a);
            cbuf[i0]         = make_float2(a0.x + t2.x, a0.y + t2.y);
            cbuf[i0 + 2 * h] = make_float2(a0.x - t2.x, a0.y - t2.y);
            float2 t3 = cmul(b1, tw2b);
            cbuf[i0 + h]     = make_float2(a1.x + t3.x, a1.y + t3.y);
            cbuf[i0 + 3 * h] = make_float2(a1.x - t3.x, a1.y - t3.y);
        }
        __syncthreads();
    }

    {
        const int h = 2048;
        const float inv = 1.0f / (float)N_;
        #pragma unroll
        for (int u = 0; u < 4; ++u) {
            const int jj = t + u * 512;
            const int i0 = jj;
            float2 c0 = cbuf[i0];
            float2 c1 = cbuf[i0 + h];
            float2 c2 = cbuf[i0 + 2 * h];
            float2 c3 = cbuf[i0 + 3 * h];
            float sa, ca;
            __sincosf(cpi * (float)jj / (float)(2 * h), &sa, &ca);
            const float2 tw1  = make_float2(2.0f * ca * ca - 1.0f, 2.0f * sa * ca);
            const float2 tw2a = make_float2(ca, sa);
            const float2 tw2b = make_float2(-sa, ca);
            float2 t0 = cmul(c1, tw1);
            float2 a0 = make_float2(c0.x + t0.x, c0.y + t0.y);
            float2 a1 = make_float2(c0.x - t0.x, c0.y - t0.y);
            float2 t1 = cmul(c3, tw1);
            float2 b0 = make_float2(c2.x + t1.x, c2.y + t1.y);
            float2 b1 = make_float2(c2.x - t1.x, c2.y - t1.y);
            float2 t2 = cmul(b0, tw2a);
            float2 o0 = make_float2(a0.x + t2.x, a0.y + t2.y);
            float2 o2 = make_float2(a0.x - t2.x, a0.y - t2.y);
            float2 t3 = cmul(b1, tw2b);
            float2 o1 = make_float2(a1.x + t3.x, a1.y + t3.y);
            float2 o3 = make_float2(a1.x - t3.x, a1.y - t3.y);
            row1[i0]         = o0.x * inv;  row2[i0]         = o0.y * inv;
            row1[i0 + h]     = o1.x * inv;  row2[i0 + h]     = o1.y * inv;
            row1[i0 + 2*h]   = o2.x * inv;  row2[i0 + 2*h]   = o2.y * inv;
            row1[i0 + 3*h]   = o3.x * inv;  row2[i0 + 3*h]   = o3.y * inv;
        }
    }
}

// ---------------------------------------------------------------------------
// K5: t[b,n,r] = sum_k y[b,k,n] * U[k,r];  out = x + t @ G^T + bu
// ---------------------------------------------------------------------------
__global__ void out_kernel(const float* __restrict__ x,
                           const float* __restrict__ y_t,
                           const float* __restrict__ U,
                           const float* __restrict__ G,
                           const float* __restrict__ bu,
                           float*       __restrict__ out) {
    __shared__ float ttile[64][R_];
    const int blk = blockIdx.x;          // 2048
    const int b   = blk >> 7;
    const int n0  = (blk & 127) << 6;
    const int t   = threadIdx.x;

    {
        const int nl = t >> 2, r = t & 3;
        const float* yb = y_t + (size_t)b * BN_ * N_ + n0 + nl;
        float s = 0.0f;
        #pragma unroll
        for (int kk = 0; kk < BN_; ++kk) s += yb[(size_t)kk * N_] * U[kk * R_ + r];
        ttile[nl][r] = s;
    }
    __syncthreads();

    float4 g = *(const float4*)(G + t * 4);
    float bv = bu[t];
    const float* xb = x   + ((size_t)b * N_ + n0) * D_;
    float*       ob = out + ((size_t)b * N_ + n0) * D_;
    for (int nl = 0; nl < 64; ++nl) {
        float t0 = ttile[nl][0], t1 = ttile[nl][1];
        float t2 = ttile[nl][2], t3 = ttile[nl][3];
        ob[nl * D_ + t] = xb[nl * D_ + t]
                        + t0 * g.x + t1 * g.y + t2 * g.z + t3 * g.w + bv;
    }
}

// ---------------------------------------------------------------------------
extern "C" void kernel_launch(void* const* d_in, const int* in_sizes, int n_in,
                              void* d_out, int out_size, void* d_ws, size_t ws_size,
                              hipStream_t stream) {
    const float* x       = (const float*)d_in[0];
    const float* coords  = (const float*)d_in[1];
    const float* Wd      = (const float*)d_in[2];
    const float* bd      = (const float*)d_in[3];
    const float* U       = (const float*)d_in[4];
    const float* V       = (const float*)d_in[5];
    const float* logit_d = (const float*)d_in[6];
    const float* Wu      = (const float*)d_in[7];
    const float* bu      = (const float*)d_in[8];
    float* out = (float*)d_out;

    char* ws = (char*)d_ws;
    int*                inv    = (int*)ws;                             // 512 KB
    unsigned long long* keys   = (unsigned long long*)(ws + 512*1024); // 1 MB
    float*              G      = (float*)(ws + 1536 * 1024);           // 4 KB
    unsigned short*     wdpack = (unsigned short*)(ws + 1792 * 1024);  // 16 KB
    float*              zpk    = (float*)(ws + 2048 * 1024);           // 16 MB
    float*              zkp    = (float*)(ws + (2048 + 16384) * 1024); // 16 MB

    prep_kernel <<<dim3(1),       dim3(256),  0, stream>>>(Wu, V, Wd, G, wdpack);
    sort1_kernel<<<dim3(2 * B_),  dim3(1024), 0, stream>>>(coords, keys);
    sort2a_kernel<<<dim3(256),    dim3(256),  0, stream>>>(keys);
    sort2b_kernel<<<dim3(2 * B_), dim3(1024), 0, stream>>>(keys, inv);
    zgemm_kernel<<<dim3(B_ * 128), dim3(256), 0, stream>>>(x, coords, Wd, bd, inv, wdpack, zpk);
    ztr_kernel  <<<dim3(B_ * 128), dim3(256), 0, stream>>>(zpk, zkp);
    fft_filter_kernel<<<dim3(B_ * 16), dim3(512), 64 * 1024, stream>>>(zkp, logit_d);
    out_kernel  <<<dim3(B_ * 128), dim3(256), 0, stream>>>(x, zkp, U, G, bu, out);
}

// Round 9
// 150.022 us; speedup vs baseline: 1.2017x; 1.2017x over previous
//
#include <hip/hip_runtime.h>
#include <math.h>

#define B_    16
#define N_    8192
#define D_    256
#define BN_   32
#define R_    4
#define LOGN  13

typedef float  f32x4  __attribute__((ext_vector_type(4)));
typedef short  s16x8  __attribute__((ext_vector_type(8)));

// ---------------------------------------------------------------------------
// Morton helpers (exact replica of reference bit-interleave)
// ---------------------------------------------------------------------------
__device__ __forceinline__ unsigned long long interleave3(unsigned long long v) {
    v = v & 2097151ULL;
    v = v | (v << 32);
    v = v & 8725724278095871ULL;
    v = v | ((v << 16) & 8725728556220671ULL);
    v = v | ((v << 8)  & 282506020581391ULL);
    v = v | ((v << 4)  & 294878547030211ULL);
    v = v | ((v << 2)  & 321685687669321ULL);
    return v;
}

__device__ __forceinline__ long long quant10(float c) {
    long long v = (long long)(c * 1023.0f);
    v = v < 0 ? 0 : (v > 1023 ? 1023 : v);
    return v;
}

__device__ __forceinline__ unsigned short f2bf(float f) {
    unsigned u = __float_as_uint(f);
    u = (u + 0x7FFF + ((u >> 16) & 1)) >> 16;   // RNE
    return (unsigned short)u;
}

__device__ __forceinline__ unsigned cvtpk_bf16(float lo, float hi) {
    unsigned r;
    asm("v_cvt_pk_bf16_f32 %0, %1, %2" : "=v"(r) : "v"(lo), "v"(hi));
    return r;
}

// ---------------------------------------------------------------------------
// P0: prep — G = Wu @ V  [256,4]  and  Wd packed to bf16 [32][256] row-major.
// ---------------------------------------------------------------------------
__global__ void prep_kernel(const float* __restrict__ Wu, const float* __restrict__ V,
                            const float* __restrict__ Wd,
                            float* __restrict__ G, unsigned short* __restrict__ wdpack) {
    const int t = threadIdx.x;   // 256
    for (int r = 0; r < R_; ++r) {
        float s = 0.0f;
        for (int kk = 0; kk < BN_; ++kk) s += Wu[t * BN_ + kk] * V[kk * R_ + r];
        G[t * R_ + r] = s;
    }
    for (int i = t; i < BN_ * 256; i += 256) {
        const int row = i >> 8, col = i & 255;
        wdpack[i] = f2bf(Wd[row * 257 + col]);
    }
}

// ---------------------------------------------------------------------------
// FAT kernel: blocks 0..31 = sort1 (local 4096-key bitonic); blocks 32.. =
// natural-order MFMA zraw = Wd·x (no order dependency -> sort hides under
// the x stream). Uniform 512 threads, 64 KB dynamic LDS.
// ---------------------------------------------------------------------------
__global__ __launch_bounds__(512)
void fat_kernel(const float* __restrict__ x,
                const float* __restrict__ coords,
                const unsigned short* __restrict__ wdpack,
                unsigned long long* __restrict__ keys,
                float* __restrict__ z_pk) {
    extern __shared__ char fsm[];
    const int bid = blockIdx.x;
    const int t   = threadIdx.x;

    if (bid < 2 * B_) {
        // ================= sort1: local bitonic, sizes 2..4096 =================
        unsigned long long* skey = (unsigned long long*)fsm;   // 32 KB
        const int b = bid >> 1;
        const int h = bid & 1;
        const int gbase = h * 4096;

        for (int i = t; i < 4096; i += 512) {
            const int gi = gbase + i;
            const float* c = coords + ((size_t)b * N_ + gi) * 3;
            unsigned long long mx = interleave3((unsigned long long)quant10(c[0]));
            unsigned long long my = interleave3((unsigned long long)quant10(c[1]));
            unsigned long long mz = interleave3((unsigned long long)quant10(c[2]));
            unsigned long long m = mx | (my << 1) | (mz << 2);
            skey[i] = (m << LOGN) | (unsigned long long)gi;
        }
        __syncthreads();

        for (int size = 2; size <= 4096; size <<= 1) {
            for (int s = size >> 1; s > 0; s >>= 1) {
                int i_[4];
                unsigned long long a_[4], b_[4];
                #pragma unroll
                for (int u = 0; u < 4; ++u) {
                    int p  = t + u * 512;            // 2048 pairs
                    int jj = p & (s - 1);
                    int i  = ((p - jj) << 1) + jj;
                    i_[u] = i; a_[u] = skey[i]; b_[u] = skey[i + s];
                }
                #pragma unroll
                for (int u = 0; u < 4; ++u) {
                    bool up = (((gbase + i_[u]) & size) == 0);
                    unsigned long long lo = a_[u] < b_[u] ? a_[u] : b_[u];
                    unsigned long long hi = a_[u] < b_[u] ? b_[u] : a_[u];
                    skey[i_[u]]     = up ? lo : hi;
                    skey[i_[u] + s] = up ? hi : lo;
                }
                __syncthreads();
            }
        }
        for (int i = t; i < 4096; i += 512)
            keys[(size_t)b * N_ + gbase + i] = skey[i];
    } else {
        // ============ zgemm_nat: 128 natural rows, pure stream ============
        char* xlds = fsm;                       // 128 rows x 512B = 64 KB
        const int zb  = bid - 2 * B_;           // 0..1023
        const int b   = zb >> 6;
        const int m0  = (zb & 63) << 7;         // 128-row tile base
        const int w   = t >> 6;
        const int l   = t & 63;
        const int lg  = l >> 4;
        const int lm  = l & 15;

        s16x8 wf0[8], wf1[8];
        #pragma unroll
        for (int kc = 0; kc < 8; ++kc) {
            wf0[kc] = *(const s16x8*)(wdpack + lm * 256        + kc * 32 + lg * 8);
            wf1[kc] = *(const s16x8*)(wdpack + (lm + 16) * 256 + kc * 32 + lg * 8);
        }

        // stage 128 rows (8 waves x 16 iterations), coalesced 1KB wave reads
        #pragma unroll 4
        for (int it = 0; it < 16; ++it) {
            const int row = it * 8 + w;
            const float4 v = *(const float4*)(x + ((size_t)(b * N_ + m0 + row)) * D_ + l * 4);
            unsigned off = (row << 9) + (l << 3);
            off ^= (row & 7) << 4;
            uint2 pk = make_uint2(cvtpk_bf16(v.x, v.y), cvtpk_bf16(v.z, v.w));
            *(uint2*)(xlds + off) = pk;
        }
        __syncthreads();

        f32x4 acc0 = {0.f, 0.f, 0.f, 0.f};
        f32x4 acc1 = {0.f, 0.f, 0.f, 0.f};
        const int xr = w * 16 + lm;
        #pragma unroll
        for (int kc = 0; kc < 8; ++kc) {
            const unsigned doff = kc * 64 + lg * 16;
            s16x8 bfr = *(const s16x8*)(xlds + ((((unsigned)xr << 9) + doff) ^ ((xr & 7) << 4)));
            acc0 = __builtin_amdgcn_mfma_f32_16x16x32_bf16(wf0[kc], bfr, acc0, 0, 0, 0);
            acc1 = __builtin_amdgcn_mfma_f32_16x16x32_bf16(wf1[kc], bfr, acc1, 0, 0, 0);
        }

        // natural-order, fully coalesced 128B-per-point store (raw, no epilogue)
        const int m = m0 + w * 16 + lm;
        float* zb_ = z_pk + ((size_t)(b * N_ + m)) * BN_;
        float4 v0, v1;
        v0.x = acc0[0]; v0.y = acc0[1]; v0.z = acc0[2]; v0.w = acc0[3];
        v1.x = acc1[0]; v1.y = acc1[1]; v1.z = acc1[2]; v1.w = acc1[3];
        *(float4*)(zb_ + lg * 4)      = v0;
        *(float4*)(zb_ + 16 + lg * 4) = v1;
    }
}

// ---------------------------------------------------------------------------
// S2a: global stride-4096 compare-swap (final merge, first stage).
// ---------------------------------------------------------------------------
__global__ __launch_bounds__(256)
void sort2a_kernel(unsigned long long* __restrict__ keys) {
    const int tid = blockIdx.x * 256 + threadIdx.x;   // 65536
    const int b = tid >> 12;
    const int i = tid & 4095;
    unsigned long long* kb = keys + (size_t)b * N_;
    unsigned long long a = kb[i], c = kb[i + 4096];
    kb[i]        = a < c ? a : c;
    kb[i + 4096] = a < c ? c : a;
}

// ---------------------------------------------------------------------------
// S2b: 32 blocks (b, half). Final-merge strides 2048..1 within each half.
// Emits order[b][p] = natural index of the p-th smallest key.
// ---------------------------------------------------------------------------
__global__ __launch_bounds__(1024)
void sort2b_kernel(const unsigned long long* __restrict__ keys, int* __restrict__ order) {
    __shared__ unsigned long long skey[4096];    // 32 KB
    const int b = blockIdx.x >> 1;
    const int h = blockIdx.x & 1;
    const int t = threadIdx.x;
    const int gbase = h * 4096;

    for (int i = t; i < 4096; i += 1024) skey[i] = keys[(size_t)b * N_ + gbase + i];
    __syncthreads();

    for (int s = 2048; s > 0; s >>= 1) {
        int i_[2];
        unsigned long long a_[2], b_[2];
        #pragma unroll
        for (int u = 0; u < 2; ++u) {
            int p  = t + u * 1024;
            int jj = p & (s - 1);
            int i  = ((p - jj) << 1) + jj;
            i_[u] = i; a_[u] = skey[i]; b_[u] = skey[i + s];
        }
        #pragma unroll
        for (int u = 0; u < 2; ++u) {
            unsigned long long lo = a_[u] < b_[u] ? a_[u] : b_[u];
            unsigned long long hi = a_[u] < b_[u] ? b_[u] : a_[u];
            skey[i_[u]]     = lo;
            skey[i_[u] + s] = hi;
        }
        __syncthreads();
    }
    for (int i = t; i < 4096; i += 1024)
        order[b * N_ + gbase + i] = (int)(skey[i] & (unsigned long long)(N_ - 1));
}

// ---------------------------------------------------------------------------
// ZG: permutation + radius + bias + relu + transpose to k-major.
// 64 sorted slots per block; reads one 128B block per point via order[p];
// writes z_kp[b][k][p] coalesced via LDS tile.
// ---------------------------------------------------------------------------
__global__ __launch_bounds__(512)
void zgather_kernel(const float* __restrict__ z_pk,
                    const float* __restrict__ coords,
                    const float* __restrict__ Wd,
                    const float* __restrict__ bd,
                    const int*   __restrict__ order,
                    float*       __restrict__ z_kp) {
    __shared__ float ltile[64][33];
    __shared__ float sWdLast[BN_];
    __shared__ float sbd[BN_];
    const int blk = blockIdx.x;           // 2048
    const int b   = blk >> 7;
    const int p0  = (blk & 127) << 6;
    const int t   = threadIdx.x;

    if (t < BN_) { sWdLast[t] = Wd[(size_t)t * 257 + 256]; sbd[t] = bd[t]; }
    __syncthreads();

    {
        const int sl = t >> 3;            // 0..63 sorted slots
        const int kc = t & 7;             // 8 float4 chunks of 32 channels
        const int p  = p0 + sl;
        const int od = order[b * N_ + p];
        float4 v = *(const float4*)(z_pk + ((size_t)(b * N_ + od)) * BN_ + kc * 4);
        const float* c = coords + ((size_t)(b * N_ + p)) * 3;
        const float rr = sqrtf(c[0] * c[0] + c[1] * c[1] + c[2] * c[2]);
        v.x = fmaxf(v.x + rr * sWdLast[kc * 4 + 0] + sbd[kc * 4 + 0], 0.0f);
        v.y = fmaxf(v.y + rr * sWdLast[kc * 4 + 1] + sbd[kc * 4 + 1], 0.0f);
        v.z = fmaxf(v.z + rr * sWdLast[kc * 4 + 2] + sbd[kc * 4 + 2], 0.0f);
        v.w = fmaxf(v.w + rr * sWdLast[kc * 4 + 3] + sbd[kc * 4 + 3], 0.0f);
        ltile[sl][kc * 4 + 0] = v.x;
        ltile[sl][kc * 4 + 1] = v.y;
        ltile[sl][kc * 4 + 2] = v.z;
        ltile[sl][kc * 4 + 3] = v.w;
    }
    __syncthreads();

    {
        const int k  = t >> 4;            // 0..31
        const int pc = t & 15;            // 16 x float4 along p
        float4 o;
        o.x = ltile[pc * 4 + 0][k];
        o.y = ltile[pc * 4 + 1][k];
        o.z = ltile[pc * 4 + 2][k];
        o.w = ltile[pc * 4 + 3][k];
        *(float4*)(z_kp + (size_t)(b * BN_ + k) * N_ + p0 + pc * 4) = o;
    }
}

// ---------------------------------------------------------------------------
// K4: PAIR-PACKED spectral filter (proven round-7 version).
// ---------------------------------------------------------------------------
__device__ __forceinline__ float2 cmul(float2 a, float2 b) {
    return make_float2(a.x * b.x - a.y * b.y, a.x * b.y + a.y * b.x);
}
__device__ __forceinline__ float2 sdmix(float S, float D, float2 P, float2 Q) {
    return make_float2(S * P.x + D * Q.x, S * P.y - D * Q.y);
}

__global__ __launch_bounds__(512)
void fft_filter_kernel(float* __restrict__ zy,
                       const float* __restrict__ logit_d) {
    extern __shared__ float2 cbuf[];   // 64 KB

    const int bk = blockIdx.x;     // 256 = B_ * 16
    const int b  = bk >> 4;
    const int kp = bk & 15;
    const int t  = threadIdx.x;

    float* row1 = zy + (size_t)(b * BN_ + 2 * kp) * N_;
    float* row2 = row1 + N_;

    float d1 = fminf(fmaxf(logit_d[2 * kp],     -10.0f), 10.0f);
    float d2 = fminf(fmaxf(logit_d[2 * kp + 1], -10.0f), 10.0f);

    const float cpi  = 3.14159265358979323846f;
    const float c2pi = 6.28318530717958647692f;
    const float A    = c2pi * 8192.0f / 8191.0f;

    const float Eh1 = __expf(-0.5f * A * d1), E1 = Eh1 * Eh1;
    const float Eh2 = __expf(-0.5f * A * d2), E2 = Eh2 * Eh2;

    {
        const int h = 4096, hh = 2048;
        #pragma unroll
        for (int u = 0; u < 4; ++u) {
            const int i0 = t + u * 512;
            float2 c0 = make_float2(row1[i0],            row2[i0]);
            float2 c1 = make_float2(row1[i0 + hh],       row2[i0 + hh]);
            float2 c2 = make_float2(row1[i0 + h],        row2[i0 + h]);
            float2 c3 = make_float2(row1[i0 + h + hh],   row2[i0 + h + hh]);
            float sA, cA;
            __sincosf(-cpi * (float)i0 / (float)h, &sA, &cA);
            const float2 twA1 = make_float2(cA, sA);
            const float2 twA2 = make_float2(sA, -cA);
            const float2 twB  = make_float2(2.0f * cA * cA - 1.0f, 2.0f * sA * cA);
            float2 a0 = make_float2(c0.x + c2.x, c0.y + c2.y);
            float2 a1 = make_float2(c1.x + c3.x, c1.y + c3.y);
            float2 b0 = cmul(make_float2(c0.x - c2.x, c0.y - c2.y), twA1);
            float2 b1 = cmul(make_float2(c1.x - c3.x, c1.y - c3.y), twA2);
            cbuf[i0]          = make_float2(a0.x + a1.x, a0.y + a1.y);
            cbuf[i0 + hh]     = cmul(make_float2(a0.x - a1.x, a0.y - a1.y), twB);
            cbuf[i0 + h]      = make_float2(b0.x + b1.x, b0.y + b1.y);
            cbuf[i0 + h + hh] = cmul(make_float2(b0.x - b1.x, b0.y - b1.y), twB);
        }
        __syncthreads();
    }

    #pragma unroll
    for (int h = 1024; h >= 4; h >>= 2) {
        const int hh = h >> 1;
        #pragma unroll
        for (int u = 0; u < 4; ++u) {
            const int q   = t + u * 512;
            const int jj  = q & (hh - 1);
            const int i0  = ((q - jj) << 2) + jj;
            float2 c0 = cbuf[i0];
            float2 c1 = cbuf[i0 + hh];
            float2 c2 = cbuf[i0 + h];
            float2 c3 = cbuf[i0 + h + hh];
            float sA, cA;
            __sincosf(-cpi * (float)jj / (float)h, &sA, &cA);
            const float2 twA1 = make_float2(cA, sA);
            const float2 twA2 = make_float2(sA, -cA);
            const float2 twB  = make_float2(2.0f * cA * cA - 1.0f, 2.0f * sA * cA);
            float2 a0 = make_float2(c0.x + c2.x, c0.y + c2.y);
            float2 a1 = make_float2(c1.x + c3.x, c1.y + c3.y);
            float2 b0 = cmul(make_float2(c0.x - c2.x, c0.y - c2.y), twA1);
            float2 b1 = cmul(make_float2(c1.x - c3.x, c1.y - c3.y), twA2);
            cbuf[i0]          = make_float2(a0.x + a1.x, a0.y + a1.y);
            cbuf[i0 + hh]     = cmul(make_float2(a0.x - a1.x, a0.y - a1.y), twB);
            cbuf[i0 + h]      = make_float2(b0.x + b1.x, b0.y + b1.y);
            cbuf[i0 + h + hh] = cmul(make_float2(b0.x - b1.x, b0.y - b1.y), twB);
        }
        __syncthreads();
    }

    {
        #pragma unroll
        for (int v = 0; v < 4; ++v) {
            const int u = t + v * 512;
            if (u == 0) {
                {
                    float2 g0 = cbuf[0], g1 = cbuf[1];
                    float2 Pa = make_float2(g0.x + g1.x, g0.y + g1.y);
                    float2 Pb = make_float2(g0.x - g1.x, g0.y - g1.y);
                    float2 Ra = Pa;
                    float Sb = 0.5f * (Eh1 + Eh2), Db = 0.5f * (Eh1 - Eh2);
                    float2 Rb = sdmix(Sb, Db, Pb, Pb);
                    cbuf[0] = make_float2(Ra.x + Rb.x, Ra.y + Rb.y);
                    cbuf[1] = make_float2(Ra.x - Rb.x, Ra.y - Rb.y);
                }
                {
                    float wu = c2pi * 2048.0f / 8191.0f;
                    float h1 = __expf(-wu * d1), h2 = __expf(-wu * d2);
                    float h1b = h1 * Eh1, h2b = h2 * Eh2;
                    float Hs1a = 0.5f * (h1 + E1 / h1);
                    float Hs2a = 0.5f * (h2 + E2 / h2);
                    float Hs1b = 0.5f * (h1b + E1 / h1b);
                    float Hs2b = 0.5f * (h2b + E2 / h2b);
                    float Sa = 0.5f * (Hs1a + Hs2a), Da = 0.5f * (Hs1a - Hs2a);
                    float Sb = 0.5f * (Hs1b + Hs2b), Db = 0.5f * (Hs1b - Hs2b);
                    float2 g0 = cbuf[2], g1 = cbuf[3];
                    float2 Pa = make_float2(g0.x + g1.x, g0.y + g1.y);
                    float2 Pb = make_float2(g0.x - g1.x, g0.y - g1.y);
                    float2 Ra = sdmix(Sa, Da, Pa, Pb);
                    float2 Rb = sdmix(Sb, Db, Pb, Pa);
                    cbuf[2] = make_float2(Ra.x + Rb.x, Ra.y + Rb.y);
                    cbuf[3] = make_float2(Ra.x - Rb.x, Ra.y - Rb.y);
                }
            } else {
                const int u2 = 4096 - u;
                const int c  = (int)(__brev((unsigned)u)  >> 20);
                const int c2 = (int)(__brev((unsigned)u2) >> 20);
                float2 g0 = cbuf[2 * c],  g1 = cbuf[2 * c + 1];
                float2 q0 = cbuf[2 * c2], q1 = cbuf[2 * c2 + 1];
                float2 Pa  = make_float2(g0.x + g1.x, g0.y + g1.y);
                float2 Pb  = make_float2(g0.x - g1.x, g0.y - g1.y);
                float2 Pa2 = make_float2(q0.x + q1.x, q0.y + q1.y);
                float2 Pb2 = make_float2(q0.x - q1.x, q0.y - q1.y);
                float wu = c2pi * (float)u / 8191.0f;
                float h1 = __expf(-wu * d1), h2 = __expf(-wu * d2);
                float h1b = h1 * Eh1, h2b = h2 * Eh2;
                float Hs1a = 0.5f * (h1 + E1 / h1);
                float Hs2a = 0.5f * (h2 + E2 / h2);
                float Hs1b = 0.5f * (h1b + E1 / h1b);
                float Hs2b = 0.5f * (h2b + E2 / h2b);
                float Sa = 0.5f * (Hs1a + Hs2a), Da = 0.5f * (Hs1a - Hs2a);
                float Sb = 0.5f * (Hs1b + Hs2b), Db = 0.5f * (Hs1b - Hs2b);
                float2 Ra  = sdmix(Sa, Da, Pa,  Pb2);
                float2 Rb2 = sdmix(Sa, Da, Pb2, Pa);
                float2 Rb  = sdmix(Sb, Db, Pb,  Pa2);
                float2 Ra2 = sdmix(Sb, Db, Pa2, Pb);
                cbuf[2 * c]      = make_float2(Ra.x + Rb.x,   Ra.y + Rb.y);
                cbuf[2 * c + 1]  = make_float2(Ra.x - Rb.x,   Ra.y - Rb.y);
                cbuf[2 * c2]     = make_float2(Ra2.x + Rb2.x, Ra2.y + Rb2.y);
                cbuf[2 * c2 + 1] = make_float2(Ra2.x - Rb2.x, Ra2.y - Rb2.y);
            }
        }
        __syncthreads();
    }

    #pragma unroll
    for (int h = 2; h <= 512; h <<= 2) {
        #pragma unroll
        for (int u = 0; u < 4; ++u) {
            const int q  = t + u * 512;
            const int jj = q & (h - 1);
            const int i0 = ((q - jj) << 2) + jj;
            float2 c0 = cbuf[i0];
            float2 c1 = cbuf[i0 + h];
            float2 c2 = cbuf[i0 + 2 * h];
            float2 c3 = cbuf[i0 + 3 * h];
            float sa, ca;
            __sincosf(cpi * (float)jj / (float)(2 * h), &sa, &ca);
            const float2 tw1  = make_float2(2.0f * ca * ca - 1.0f, 2.0f * sa * ca);
            const float2 tw2a = make_float2(ca, sa);
            const float2 tw2b = make_float2(-sa, ca);
            float2 t0 = cmul(c1, tw1);
            float2 a0 = make_float2(c0.x + t0.x, c0.y + t0.y);
            float2 a1 = make_float2(c0.x - t0.x, c0.y - t0.y);
            float2 t1 = cmul(c3, tw1);
            float2 b0 = make_float2(c2.x + t1.x, c2.y + t1.y);
            float2 b1 = make_float2(c2.x - t1.x, c2.y - t1.y);
            float2 t2 = cmul(b0, tw2a);
            cbuf[i0]         = make_float2(a0.x + t2.x, a0.y + t2.y);
            cbuf[i0 + 2 * h] = make_float2(a0.x - t2.x, a0.y - t2.y);
            float2 t3 = cmul(b1, tw2b);
            cbuf[i0 + h]     = make_float2(a1.x + t3.x, a1.y + t3.y);
            cbuf[i0 + 3 * h] = make_float2(a1.x - t3.x, a1.y - t3.y);
        }
        __syncthreads();
    }

    {
        const int h = 2048;
        const float inv = 1.0f / (float)N_;
        #pragma unroll
        for (int u = 0; u < 4; ++u) {
            const int jj = t + u * 512;
            const int i0 = jj;
            float2 c0 = cbuf[i0];
            float2 c1 = cbuf[i0 + h];
            float2 c2 = cbuf[i0 + 2 * h];
            float2 c3 = cbuf[i0 + 3 * h];
            float sa, ca;
            __sincosf(cpi * (float)jj / (float)(2 * h), &sa, &ca);
            const float2 tw1  = make_float2(2.0f * ca * ca - 1.0f, 2.0f * sa * ca);
            const float2 tw2a = make_float2(ca, sa);
            const float2 tw2b = make_float2(-sa, ca);
            float2 t0 = cmul(c1, tw1);
            float2 a0 = make_float2(c0.x + t0.x, c0.y + t0.y);
            float2 a1 = make_float2(c0.x - t0.x, c0.y - t0.y);
            float2 t1 = cmul(c3, tw1);
            float2 b0 = make_float2(c2.x + t1.x, c2.y + t1.y);
            float2 b1 = make_float2(c2.x - t1.x, c2.y - t1.y);
            float2 t2 = cmul(b0, tw2a);
            float2 o0 = make_float2(a0.x + t2.x, a0.y + t2.y);
            float2 o2 = make_float2(a0.x - t2.x, a0.y - t2.y);
            float2 t3 = cmul(b1, tw2b);
            float2 o1 = make_float2(a1.x + t3.x, a1.y + t3.y);
            float2 o3 = make_float2(a1.x - t3.x, a1.y - t3.y);
            row1[i0]         = o0.x * inv;  row2[i0]         = o0.y * inv;
            row1[i0 + h]     = o1.x * inv;  row2[i0 + h]     = o1.y * inv;
            row1[i0 + 2*h]   = o2.x * inv;  row2[i0 + 2*h]   = o2.y * inv;
            row1[i0 + 3*h]   = o3.x * inv;  row2[i0 + 3*h]   = o3.y * inv;
        }
    }
}

// ---------------------------------------------------------------------------
// K5: t[b,n,r] = sum_k y[b,k,n] * U[k,r];  out = x + t @ G^T + bu
// ---------------------------------------------------------------------------
__global__ void out_kernel(const float* __restrict__ x,
                           const float* __restrict__ y_t,
                           const float* __restrict__ U,
                           const float* __restrict__ G,
                           const float* __restrict__ bu,
                           float*       __restrict__ out) {
    __shared__ float ttile[64][R_];
    const int blk = blockIdx.x;          // 2048
    const int b   = blk >> 7;
    const int n0  = (blk & 127) << 6;
    const int t   = threadIdx.x;

    {
        const int nl = t >> 2, r = t & 3;
        const float* yb = y_t + (size_t)b * BN_ * N_ + n0 + nl;
        float s = 0.0f;
        #pragma unroll
        for (int kk = 0; kk < BN_; ++kk) s += yb[(size_t)kk * N_] * U[kk * R_ + r];
        ttile[nl][r] = s;
    }
    __syncthreads();

    float4 g = *(const float4*)(G + t * 4);
    float bv = bu[t];
    const float* xb = x   + ((size_t)b * N_ + n0) * D_;
    float*       ob = out + ((size_t)b * N_ + n0) * D_;
    for (int nl = 0; nl < 64; ++nl) {
        float t0 = ttile[nl][0], t1 = ttile[nl][1];
        float t2 = ttile[nl][2], t3 = ttile[nl][3];
        ob[nl * D_ + t] = xb[nl * D_ + t]
                        + t0 * g.x + t1 * g.y + t2 * g.z + t3 * g.w + bv;
    }
}

// ---------------------------------------------------------------------------
extern "C" void kernel_launch(void* const* d_in, const int* in_sizes, int n_in,
                              void* d_out, int out_size, void* d_ws, size_t ws_size,
                              hipStream_t stream) {
    const float* x       = (const float*)d_in[0];
    const float* coords  = (const float*)d_in[1];
    const float* Wd      = (const float*)d_in[2];
    const float* bd      = (const float*)d_in[3];
    const float* U       = (const float*)d_in[4];
    const float* V       = (const float*)d_in[5];
    const float* logit_d = (const float*)d_in[6];
    const float* Wu      = (const float*)d_in[7];
    const float* bu      = (const float*)d_in[8];
    float* out = (float*)d_out;

    char* ws = (char*)d_ws;
    int*                order  = (int*)ws;                             // 512 KB
    unsigned long long* keys   = (unsigned long long*)(ws + 512*1024); // 1 MB
    float*              G      = (float*)(ws + 1536 * 1024);           // 4 KB
    unsigned short*     wdpack = (unsigned short*)(ws + 1792 * 1024);  // 16 KB
    float*              zpk    = (float*)(ws + 2048 * 1024);           // 16 MB
    float*              zkp    = (float*)(ws + (2048 + 16384) * 1024); // 16 MB

    prep_kernel  <<<dim3(1),              dim3(256),  0, stream>>>(Wu, V, Wd, G, wdpack);
    fat_kernel   <<<dim3(2 * B_ + 1024),  dim3(512),  64 * 1024, stream>>>(x, coords, wdpack, keys, zpk);
    sort2a_kernel<<<dim3(256),            dim3(256),  0, stream>>>(keys);
    sort2b_kernel<<<dim3(2 * B_),         dim3(1024), 0, stream>>>(keys, order);
    zgather_kernel<<<dim3(B_ * 128),      dim3(512),  0, stream>>>(zpk, coords, Wd, bd, order, zkp);
    fft_filter_kernel<<<dim3(B_ * 16),    dim3(512),  64 * 1024, stream>>>(zkp, logit_d);
    out_kernel   <<<dim3(B_ * 128),       dim3(256),  0, stream>>>(x, zkp, U, G, bu, out);
}